// Round 7
// baseline (1390.784 us; speedup 1.0000x reference)
//
#include <hip/hip_runtime.h>
#include <hip/hip_bf16.h>

// 3-layer stacked LSTM forward (eval). Round 7: MFMA recurrent scans.
//  - scan1/scan2: 16 batch-rows per block, h[16xH]*Whh^T per step via
//    mfma_f32_16x16x32_bf16. Wave w owns units [16w,16w+16); its 4 n-tiles are
//    gate rows {u,u+H,u+2H,u+3H} -> i,f,g,o of a cell land in the SAME lane
//    (C layout col=lane&15,row=(lane>>4)*4+r) -> register-local cell update,
//    no gate exchange, ONE barrier/step. xg[t] enters as the MFMA C operand.
//    h recirculates via XOR-swizzled LDS (2B swz writes, b128 swz reads).
//    Weights pinned in VGPR (asm) + __launch_bounds__(...,2) vs r6 sinking.
//  - gemm_mfma (bf16 128x128 swizzled), gemm_xg3, scan3 ring: unchanged.
// T=512, B=256, IN=97(pad128), H1=128, H2=64, H3=1.

#define T_TOT 512
#define BB    256
#define CH    128
#define NCH   4

typedef __attribute__((ext_vector_type(8))) short  short8v;   // 8 bf16
typedef __attribute__((ext_vector_type(4))) float  float4v;   // MFMA acc

__device__ __forceinline__ float sigm(float x) {
    float e = __expf(-x);
    return __builtin_amdgcn_rcpf(1.0f + e);
}
__device__ __forceinline__ float tanh_(float x) {
    float e = __expf(2.0f * x);
    return 1.0f - 2.0f * __builtin_amdgcn_rcpf(1.0f + e);
}
__device__ __forceinline__ unsigned short f2bf(float x) {
    __hip_bfloat16 b = __float2bfloat16(x);
    return __builtin_bit_cast(unsigned short, b);
}

// ---------------------------------------------------------------------------
__global__ __launch_bounds__(256) void cvt_pad(
    const float* __restrict__ in, __hip_bfloat16* __restrict__ out, int R, int K)
{
    int total = R * 128;
    for (int idx = blockIdx.x * 256 + threadIdx.x; idx < total; idx += gridDim.x * 256) {
        int r = idx >> 7, c = idx & 127;
        float v = (c < K) ? in[(size_t)r * K + c] : 0.0f;
        out[idx] = __float2bfloat16(v);
    }
}
__global__ __launch_bounds__(256) void cvt_plain(
    const float* __restrict__ in, __hip_bfloat16* __restrict__ out, int n)
{
    int i = blockIdx.x * 256 + threadIdx.x;
    if (i < n) out[i] = __float2bfloat16(in[i]);
}
__global__ __launch_bounds__(256) void addvec(
    const float* __restrict__ a, const float* __restrict__ b, float* __restrict__ o, int n)
{
    int i = blockIdx.x * 256 + threadIdx.x;
    if (i < n) o[i] = a[i] + b[i];
}

// ---------------------------------------------------------------------------
// bf16 MFMA GEMM (unchanged): C[M,N] = A[M,128] * W[N,128]^T + bias
// ---------------------------------------------------------------------------
__global__ __launch_bounds__(256) void gemm_mfma(
    const __hip_bfloat16* __restrict__ A,
    const __hip_bfloat16* __restrict__ W,
    const float* __restrict__ bias,
    float* __restrict__ C, int N)
{
    __shared__ __hip_bfloat16 At[128 * 128];   // 32 KB

    const int tid  = threadIdx.x;
    const int lane = tid & 63;
    const int wid  = tid >> 6;
    const int m0   = blockIdx.x * 128;
    const int n0   = blockIdx.y * 128;
    const int wr   = wid >> 1;
    const int wc   = wid & 1;

    short8v bfrag[4][4];  // [nf][kf]
    {
        const char* Wg = (const char*)W;
#pragma unroll
        for (int nf = 0; nf < 4; ++nf) {
            int row = n0 + wc * 64 + nf * 16 + (lane & 15);
#pragma unroll
            for (int kf = 0; kf < 4; ++kf) {
                int colb = (kf * 32 + (lane >> 4) * 8) * 2;
                bfrag[nf][kf] = *(const short8v*)(Wg + (size_t)row * 256 + colb);
            }
        }
    }
    {
        const char* Ag = (const char*)(A + (size_t)m0 * 128);
        char* As = (char*)At;
#pragma unroll
        for (int r2 = 0; r2 < 8; ++r2) {
            int off = r2 * 4096 + tid * 16;
            int row = off >> 8;
            int bir = off & 255;
            short8v v = *(const short8v*)(Ag + (size_t)row * 256 + bir);
            int sw = bir ^ ((row & 7) << 4);
            *(short8v*)(As + row * 256 + sw) = v;
        }
    }
    __syncthreads();

    float4v acc[4][4] = {};
#pragma unroll
    for (int kf = 0; kf < 4; ++kf) {
        short8v af[4];
#pragma unroll
        for (int mf = 0; mf < 4; ++mf) {
            int row   = wr * 64 + mf * 16 + (lane & 15);
            int kbyte = kf * 64 + (lane >> 4) * 16;
            int sw    = kbyte ^ ((row & 7) << 4);
            af[mf] = *(const short8v*)((const char*)At + row * 256 + sw);
        }
#pragma unroll
        for (int mf = 0; mf < 4; ++mf)
#pragma unroll
            for (int nf = 0; nf < 4; ++nf)
                acc[mf][nf] = __builtin_amdgcn_mfma_f32_16x16x32_bf16(
                    af[mf], bfrag[nf][kf], acc[mf][nf], 0, 0, 0);
    }

#pragma unroll
    for (int nf = 0; nf < 4; ++nf) {
        int col = n0 + wc * 64 + nf * 16 + (lane & 15);
        float bv = bias[col];
#pragma unroll
        for (int mf = 0; mf < 4; ++mf) {
            int rbase = m0 + wr * 64 + mf * 16 + (lane >> 4) * 4;
#pragma unroll
            for (int r = 0; r < 4; ++r)
                C[(size_t)(rbase + r) * N + col] = acc[mf][nf][r] + bv;
        }
    }
}

// ---------------------------------------------------------------------------
// scan1 (H=128): 16 blocks x 512 thr (8 waves). Block owns batch rows
// [16*bid,16*bid+16). Wave wid owns units u0=16*wid..+15. Per step:
// mfma(h-frag, Whh-frag, acc=xg) for 4 gate-tiles x 4 k-tiles.
// ---------------------------------------------------------------------------
__global__ __launch_bounds__(512, 2) void lstm_scan1(
    const float* __restrict__ xg,            // [Tc, BB, 512] f32, bias incl.
    const __hip_bfloat16* __restrict__ Wh,   // [512, 128] bf16
    __hip_bfloat16* __restrict__ hout,       // [Tc, BB, 128]
    float* __restrict__ hstate, float* __restrict__ cstate,
    int Tc, int first)
{
    const int tid  = threadIdx.x;
    const int lane = tid & 63;
    const int wid  = tid >> 6;
    const int br0  = blockIdx.x * 16;
    const int u0   = wid * 16;
    const int myu  = u0 + (lane & 15);

    __shared__ __align__(16) char hb[2][4096];   // [2][16 rows][128 units] bf16, swizzled

    // ---- B-frags: gate rows {G*128 + myu}, pinned in VGPR ----
    uint4 wf[4][4];
    {
        const char* Wg = (const char*)Wh;
#pragma unroll
        for (int G = 0; G < 4; ++G) {
            int row = G * 128 + myu;
#pragma unroll
            for (int kf = 0; kf < 4; ++kf)
                wf[G][kf] = *(const uint4*)(Wg + (size_t)row * 256 + (kf * 32 + (lane >> 4) * 8) * 2);
        }
    }
#pragma unroll
    for (int G = 0; G < 4; ++G)
#pragma unroll
        for (int kf = 0; kf < 4; ++kf)
            asm volatile("" : "+v"(wf[G][kf].x), "+v"(wf[G][kf].y),
                              "+v"(wf[G][kf].z), "+v"(wf[G][kf].w));

    // ---- state init ----
    float c[4], hlast[4];
#pragma unroll
    for (int r = 0; r < 4; ++r) {
        int br = (lane >> 4) * 4 + r;
        c[r]     = first ? 0.0f : cstate[(size_t)(br0 + br) * 128 + myu];
        hlast[r] = first ? 0.0f : hstate[(size_t)(br0 + br) * 128 + myu];
    }
#pragma unroll
    for (int j = 0; j < 4; ++j) {
        int idx = tid + j * 512;          // 0..2047
        int row = idx >> 7, u = idx & 127;
        float hv = first ? 0.0f : hstate[(size_t)(br0 + row) * 128 + u];
        int byte = (row * 256 + u * 2) ^ ((row & 7) << 4);
        *(unsigned short*)(hb[0] + byte) = f2bf(hv);
    }
    __syncthreads();

    // ---- xg addressing: (t*BB + br0 + (lane>>4)*4 + r)*512 + G*128 + myu ----
    const float* xbase = xg + (size_t)(br0 + (lane >> 4) * 4) * 512 + myu;
    float4v xgc[4], xgn[4];
#pragma unroll
    for (int G = 0; G < 4; ++G)
#pragma unroll
        for (int r = 0; r < 4; ++r)
            xgc[G][r] = xbase[(size_t)r * 512 + G * 128];

    int cur = 0;
    for (int t = 0; t < Tc; ++t) {
        // A-frags from hb[cur]
        short8v af[4];
#pragma unroll
        for (int kf = 0; kf < 4; ++kf) {
            int row  = lane & 15;
            int byte = (row * 256 + kf * 64 + (lane >> 4) * 16) ^ ((row & 7) << 4);
            af[kf] = *(const short8v*)(hb[cur] + byte);
        }
        // prefetch next xg
        if (t + 1 < Tc) {
            const float* xn = xbase + (size_t)(t + 1) * BB * 512;
#pragma unroll
            for (int G = 0; G < 4; ++G)
#pragma unroll
                for (int r = 0; r < 4; ++r)
                    xgn[G][r] = xn[(size_t)r * 512 + G * 128];
        }
        // MFMA: acc[G] = xg + h*Whh_G
        float4v acc[4];
#pragma unroll
        for (int G = 0; G < 4; ++G) {
            acc[G] = xgc[G];
#pragma unroll
            for (int kf = 0; kf < 4; ++kf)
                acc[G] = __builtin_amdgcn_mfma_f32_16x16x32_bf16(
                    af[kf], __builtin_bit_cast(short8v, wf[G][kf]), acc[G], 0, 0, 0);
        }
        // epilogue: register-local cell update (i,f,g,o same lane)
#pragma unroll
        for (int r = 0; r < 4; ++r) {
            float i_ = sigm(acc[0][r]);
            float f_ = sigm(acc[1][r]);
            float g_ = tanh_(acc[2][r]);
            float o_ = sigm(acc[3][r]);
            c[r] = fmaf(f_, c[r], i_ * g_);
            float h = o_ * tanh_(c[r]);
            hlast[r] = h;
            unsigned short h16 = f2bf(h);
            int br   = (lane >> 4) * 4 + r;
            int byte = (br * 256 + myu * 2) ^ ((br & 7) << 4);
            *(unsigned short*)(hb[cur ^ 1] + byte) = h16;
            ((unsigned short*)hout)[((size_t)t * BB + br0 + br) * 128 + myu] = h16;
        }
        __syncthreads();
        cur ^= 1;
#pragma unroll
        for (int G = 0; G < 4; ++G) xgc[G] = xgn[G];
    }

#pragma unroll
    for (int r = 0; r < 4; ++r) {
        int br = (lane >> 4) * 4 + r;
        cstate[(size_t)(br0 + br) * 128 + myu] = c[r];
        hstate[(size_t)(br0 + br) * 128 + myu] = hlast[r];
    }
}

// ---------------------------------------------------------------------------
// scan2 (H=64): 16 blocks x 256 thr (4 waves). Same scheme, K=64 (2 k-tiles).
// f32 h output (feeds fp32 gemm_xg3).
// ---------------------------------------------------------------------------
__global__ __launch_bounds__(256, 1) void lstm_scan2(
    const float* __restrict__ xg,            // [Tc, BB, 256]
    const __hip_bfloat16* __restrict__ Wh,   // [256, 64] bf16
    float* __restrict__ hout,                // [Tc, BB, 64] f32
    float* __restrict__ hstate, float* __restrict__ cstate,
    int Tc, int first)
{
    const int tid  = threadIdx.x;
    const int lane = tid & 63;
    const int wid  = tid >> 6;
    const int br0  = blockIdx.x * 16;
    const int u0   = wid * 16;
    const int myu  = u0 + (lane & 15);

    __shared__ __align__(16) char hb[2][2048];   // [2][16 rows][64 units] bf16, swizzled

    uint4 wf[4][2];
    {
        const char* Wg = (const char*)Wh;
#pragma unroll
        for (int G = 0; G < 4; ++G) {
            int row = G * 64 + myu;
#pragma unroll
            for (int kf = 0; kf < 2; ++kf)
                wf[G][kf] = *(const uint4*)(Wg + (size_t)row * 128 + (kf * 32 + (lane >> 4) * 8) * 2);
        }
    }
#pragma unroll
    for (int G = 0; G < 4; ++G)
#pragma unroll
        for (int kf = 0; kf < 2; ++kf)
            asm volatile("" : "+v"(wf[G][kf].x), "+v"(wf[G][kf].y),
                              "+v"(wf[G][kf].z), "+v"(wf[G][kf].w));

    float c[4], hlast[4];
#pragma unroll
    for (int r = 0; r < 4; ++r) {
        int br = (lane >> 4) * 4 + r;
        c[r]     = first ? 0.0f : cstate[(size_t)(br0 + br) * 64 + myu];
        hlast[r] = first ? 0.0f : hstate[(size_t)(br0 + br) * 64 + myu];
    }
#pragma unroll
    for (int j = 0; j < 4; ++j) {
        int idx = tid + j * 256;          // 0..1023
        int row = idx >> 6, u = idx & 63;
        float hv = first ? 0.0f : hstate[(size_t)(br0 + row) * 64 + u];
        int byte = (row * 128 + u * 2) ^ ((row & 7) << 4);
        *(unsigned short*)(hb[0] + byte) = f2bf(hv);
    }
    __syncthreads();

    const float* xbase = xg + (size_t)(br0 + (lane >> 4) * 4) * 256 + myu;
    float4v xgc[4], xgn[4];
#pragma unroll
    for (int G = 0; G < 4; ++G)
#pragma unroll
        for (int r = 0; r < 4; ++r)
            xgc[G][r] = xbase[(size_t)r * 256 + G * 64];

    int cur = 0;
    for (int t = 0; t < Tc; ++t) {
        short8v af[2];
#pragma unroll
        for (int kf = 0; kf < 2; ++kf) {
            int row  = lane & 15;
            int byte = (row * 128 + kf * 64 + (lane >> 4) * 16) ^ ((row & 7) << 4);
            af[kf] = *(const short8v*)(hb[cur] + byte);
        }
        if (t + 1 < Tc) {
            const float* xn = xbase + (size_t)(t + 1) * BB * 256;
#pragma unroll
            for (int G = 0; G < 4; ++G)
#pragma unroll
                for (int r = 0; r < 4; ++r)
                    xgn[G][r] = xn[(size_t)r * 256 + G * 64];
        }
        float4v acc[4];
#pragma unroll
        for (int G = 0; G < 4; ++G) {
            acc[G] = xgc[G];
#pragma unroll
            for (int kf = 0; kf < 2; ++kf)
                acc[G] = __builtin_amdgcn_mfma_f32_16x16x32_bf16(
                    af[kf], __builtin_bit_cast(short8v, wf[G][kf]), acc[G], 0, 0, 0);
        }
#pragma unroll
        for (int r = 0; r < 4; ++r) {
            float i_ = sigm(acc[0][r]);
            float f_ = sigm(acc[1][r]);
            float g_ = tanh_(acc[2][r]);
            float o_ = sigm(acc[3][r]);
            c[r] = fmaf(f_, c[r], i_ * g_);
            float h = o_ * tanh_(c[r]);
            hlast[r] = h;
            int br   = (lane >> 4) * 4 + r;
            int byte = (br * 128 + myu * 2) ^ ((br & 7) << 4);
            *(unsigned short*)(hb[cur ^ 1] + byte) = f2bf(h);
            hout[((size_t)t * BB + br0 + br) * 64 + myu] = h;
        }
        __syncthreads();
        cur ^= 1;
#pragma unroll
        for (int G = 0; G < 4; ++G) xgc[G] = xgn[G];
    }

#pragma unroll
    for (int r = 0; r < 4; ++r) {
        int br = (lane >> 4) * 4 + r;
        cstate[(size_t)(br0 + br) * 64 + myu] = c[r];
        hstate[(size_t)(br0 + br) * 64 + myu] = hlast[r];
    }
}

// ---------------------------------------------------------------------------
// Layer-3 GEMM (fp32, unchanged)
// ---------------------------------------------------------------------------
__global__ __launch_bounds__(256) void gemm_xg3(
    const float* __restrict__ X, const float* __restrict__ W,
    const float* __restrict__ b1, const float* __restrict__ b2,
    float* __restrict__ out)
{
    __shared__ __align__(16) float ws4[4][64];
    __shared__ float bb[4];
    const int tid = threadIdx.x;
    {
        const int nn = tid >> 6, kk = tid & 63;
        ws4[nn][kk] = W[nn * 64 + kk];
    }
    if (tid < 4) bb[tid] = b1[tid] + b2[tid];
    __syncthreads();

    const int m = blockIdx.x * 256 + tid;
    const float4* xr = reinterpret_cast<const float4*>(X + (size_t)m * 64);
    float a0 = bb[0], a1 = bb[1], a2 = bb[2], a3 = bb[3];
#pragma unroll
    for (int kk = 0; kk < 16; ++kk) {
        float4 xv = xr[kk];
        float4 w0 = *reinterpret_cast<const float4*>(&ws4[0][4 * kk]);
        float4 w1 = *reinterpret_cast<const float4*>(&ws4[1][4 * kk]);
        float4 w2 = *reinterpret_cast<const float4*>(&ws4[2][4 * kk]);
        float4 w3 = *reinterpret_cast<const float4*>(&ws4[3][4 * kk]);
        a0 = fmaf(xv.x, w0.x, a0); a0 = fmaf(xv.y, w0.y, a0); a0 = fmaf(xv.z, w0.z, a0); a0 = fmaf(xv.w, w0.w, a0);
        a1 = fmaf(xv.x, w1.x, a1); a1 = fmaf(xv.y, w1.y, a1); a1 = fmaf(xv.z, w1.z, a1); a1 = fmaf(xv.w, w1.w, a1);
        a2 = fmaf(xv.x, w2.x, a2); a2 = fmaf(xv.y, w2.y, a2); a2 = fmaf(xv.z, w2.z, a2); a2 = fmaf(xv.w, w2.w, a2);
        a3 = fmaf(xv.x, w3.x, a3); a3 = fmaf(xv.y, w3.y, a3); a3 = fmaf(xv.z, w3.z, a3); a3 = fmaf(xv.w, w3.w, a3);
    }
    float4 o; o.x = a0; o.y = a1; o.z = a2; o.w = a3;
    *reinterpret_cast<float4*>(&out[(size_t)m * 4]) = o;
}

// ---------------------------------------------------------------------------
// Layer-3 scan: 8-deep static prefetch ring (unchanged).
// ---------------------------------------------------------------------------
__global__ __launch_bounds__(256) void lstm_scan3(
    const float* __restrict__ xg,   // [T, B, 4]
    const float* __restrict__ Whh,  // [4, 1]
    float* __restrict__ out,        // [T, B]
    int T)
{
    const int b = threadIdx.x;
    const float w0 = Whh[0], w1 = Whh[1], w2 = Whh[2], w3 = Whh[3];
    float h = 0.0f, c = 0.0f;
    const float4* p = reinterpret_cast<const float4*>(xg) + b;

    float4 cur[8], nxt[8];
#pragma unroll
    for (int j = 0; j < 8; ++j) cur[j] = p[(size_t)j * BB];

    for (int t0 = 0; t0 < T; t0 += 8) {
#pragma unroll
        for (int j = 0; j < 8; ++j) {
            int tt = t0 + 8 + j;
            if (tt < T) nxt[j] = p[(size_t)tt * BB];
        }
#pragma unroll
        for (int j = 0; j < 8; ++j) {
            float4 g4 = cur[j];
            float gi = fmaf(h, w0, g4.x);
            float gf = fmaf(h, w1, g4.y);
            float gg = fmaf(h, w2, g4.z);
            float go = fmaf(h, w3, g4.w);
            float i_ = sigm(gi);
            float f_ = sigm(gf);
            float g_ = tanh_(gg);
            float o_ = sigm(go);
            c = fmaf(f_, c, i_ * g_);
            h = o_ * tanh_(c);
            out[(size_t)(t0 + j) * BB + b] = h;
        }
#pragma unroll
        for (int j = 0; j < 8; ++j) cur[j] = nxt[j];
    }
}

// ---------------------------------------------------------------------------
extern "C" void kernel_launch(void* const* d_in, const int* in_sizes, int n_in,
                              void* d_out, int out_size, void* d_ws, size_t ws_size,
                              hipStream_t stream) {
    const float* x    = (const float*)d_in[0];
    const float* Wih1 = (const float*)d_in[1];
    const float* Whh1 = (const float*)d_in[2];
    const float* bih1 = (const float*)d_in[3];
    const float* bhh1 = (const float*)d_in[4];
    const float* Wih2 = (const float*)d_in[5];
    const float* Whh2 = (const float*)d_in[6];
    const float* bih2 = (const float*)d_in[7];
    const float* bhh2 = (const float*)d_in[8];
    const float* Wih3 = (const float*)d_in[9];
    const float* Whh3 = (const float*)d_in[10];
    const float* bih3 = (const float*)d_in[11];
    const float* bhh3 = (const float*)d_in[12];
    float* out = (float*)d_out;

    char* ws = (char*)d_ws;
    // Workspace (~171 MB). xb aliases h2 (disjoint phases).
    float*           xg1c  = (float*)(ws + 0);                   // 67,108,864
    __hip_bfloat16*  h1b   = (__hip_bfloat16*)(ws + 67108864);   // 33,554,432
    float*           xg2c  = (float*)(ws + 100663296);           // 33,554,432
    float*           h2    = (float*)(ws + 134217728);           // 33,554,432
    __hip_bfloat16*  xb    = (__hip_bfloat16*)(ws + 134217728);  // alias of h2
    float*           xg3   = (float*)(ws + 167772160);           //  2,097,152
    __hip_bfloat16*  wb1   = (__hip_bfloat16*)(ws + 169869312);  //   131,072
    __hip_bfloat16*  wb2   = (__hip_bfloat16*)(ws + 170000384);  //    65,536
    __hip_bfloat16*  whb1  = (__hip_bfloat16*)(ws + 170065920);  //   131,072 (Whh1 bf16)
    __hip_bfloat16*  whb2  = (__hip_bfloat16*)(ws + 170196992);  //    32,768 (Whh2 bf16)
    float*           bias1 = (float*)(ws + 170229760);           //     2,048
    float*           bias2 = (float*)(ws + 170231808);           //     1,024
    float*           st1h  = (float*)(ws + 170232832);
    float*           st1c  = st1h + BB * 128;
    float*           st2h  = st1c + BB * 128;
    float*           st2c  = st2h + BB * 64;

    // ---- P0: conversions ----
    cvt_pad<<<4096, 256, 0, stream>>>(x, xb, T_TOT * BB, 97);
    cvt_pad<<<256, 256, 0, stream>>>(Wih1, wb1, 512, 97);
    cvt_pad<<<128, 256, 0, stream>>>(Wih2, wb2, 256, 128);
    cvt_pad<<<256, 256, 0, stream>>>(Whh1, whb1, 512, 128);
    cvt_plain<<<64, 256, 0, stream>>>(Whh2, whb2, 256 * 64);
    addvec<<<2, 256, 0, stream>>>(bih1, bhh1, bias1, 512);
    addvec<<<1, 256, 0, stream>>>(bih2, bhh2, bias2, 256);

    // ---- P1: Layer 1 (chunked over T) ----
    for (int c0 = 0; c0 < NCH; ++c0) {
        gemm_mfma<<<dim3(CH * BB / 128, 512 / 128), 256, 0, stream>>>(
            xb + (size_t)c0 * CH * BB * 128, wb1, bias1, xg1c, 512);
        lstm_scan1<<<16, 512, 0, stream>>>(
            xg1c, whb1, h1b + (size_t)c0 * CH * BB * 128, st1h, st1c, CH, c0 == 0);
    }
    // ---- P2: Layer 2 (chunked over T) ----
    for (int c0 = 0; c0 < NCH; ++c0) {
        gemm_mfma<<<dim3(CH * BB / 128, 256 / 128), 256, 0, stream>>>(
            h1b + (size_t)c0 * CH * BB * 128, wb2, bias2, xg2c, 256);
        lstm_scan2<<<16, 256, 0, stream>>>(
            xg2c, whb2, h2 + (size_t)c0 * CH * BB * 64, st2h, st2c, CH, c0 == 0);
    }
    // ---- P3: Layer 3 ----
    gemm_xg3<<<T_TOT * BB / 256, 256, 0, stream>>>(h2, Wih3, bih3, bhh3, xg3);
    lstm_scan3<<<1, 256, 0, stream>>>(xg3, Whh3, out, T_TOT);
}

// Round 8
// 1123.700 us; speedup vs baseline: 1.2377x; 1.2377x over previous
//
#include <hip/hip_runtime.h>
#include <hip/hip_bf16.h>

// 3-layer stacked LSTM forward (eval). Round 8: FULLY FUSED scans.
//  - scan1_fused: per step, xacc = bias1 + x[t]*Wih1^T (MFMA, pipelined 1 step
//    ahead; x-frags from global, 2-deep prefetch) and preact = xacc + h*Whh1^T
//    (MFMA). No xg buffer AT ALL. Both weight sets in registers/AGPRs, pinned.
//  - scan23_fused: same scheme for layer 2 (waves 0-3) + layer 3 on wave 4
//    (f32 LDS h2 ring, f32 Wih3 dots + h3*Whh3 recurrence term, scalar
//    recurrence per batch row in lanes 0-15). gemm_mfma/gemm_xg3/scan3 DELETED.
//  - No chunking (no xg workspace): 1 dispatch per layer-kernel.
// T=512, B=256, IN=97(pad128), H1=128, H2=64, H3=1.

#define T_TOT 512
#define BB    256

typedef __attribute__((ext_vector_type(8))) short  short8v;   // 8 bf16
typedef __attribute__((ext_vector_type(4))) float  float4v;   // MFMA acc

__device__ __forceinline__ float sigm(float x) {
    float e = __expf(-x);
    return __builtin_amdgcn_rcpf(1.0f + e);
}
__device__ __forceinline__ float tanh_(float x) {
    float e = __expf(2.0f * x);
    return 1.0f - 2.0f * __builtin_amdgcn_rcpf(1.0f + e);
}
__device__ __forceinline__ unsigned short f2bf(float x) {
    __hip_bfloat16 b = __float2bfloat16(x);
    return __builtin_bit_cast(unsigned short, b);
}

// ---------------------------------------------------------------------------
__global__ __launch_bounds__(256) void cvt_pad(
    const float* __restrict__ in, __hip_bfloat16* __restrict__ out, int R, int K)
{
    int total = R * 128;
    for (int idx = blockIdx.x * 256 + threadIdx.x; idx < total; idx += gridDim.x * 256) {
        int r = idx >> 7, c = idx & 127;
        float v = (c < K) ? in[(size_t)r * K + c] : 0.0f;
        out[idx] = __float2bfloat16(v);
    }
}
__global__ __launch_bounds__(256) void cvt_plain(
    const float* __restrict__ in, __hip_bfloat16* __restrict__ out, int n)
{
    int i = blockIdx.x * 256 + threadIdx.x;
    if (i < n) out[i] = __float2bfloat16(in[i]);
}
__global__ __launch_bounds__(256) void addvec(
    const float* __restrict__ a, const float* __restrict__ b, float* __restrict__ o, int n)
{
    int i = blockIdx.x * 256 + threadIdx.x;
    if (i < n) o[i] = a[i] + b[i];
}

// ---------------------------------------------------------------------------
// scan1_fused (H=128): 16 blocks x 512 thr (8 waves).
// ---------------------------------------------------------------------------
__global__ __launch_bounds__(512, 2) void scan1_fused(
    const __hip_bfloat16* __restrict__ xb,   // [T, BB, 128] bf16 (padded)
    const __hip_bfloat16* __restrict__ Wx,   // [512, 128] Wih1 bf16 (padded)
    const __hip_bfloat16* __restrict__ Wh,   // [512, 128] Whh1 bf16
    const float* __restrict__ bias,          // [512] bih1+bhh1
    __hip_bfloat16* __restrict__ hout)       // [T, BB, 128]
{
    const int tid  = threadIdx.x;
    const int lane = tid & 63;
    const int wid  = tid >> 6;
    const int br0  = blockIdx.x * 16;
    const int myu  = wid * 16 + (lane & 15);

    __shared__ __align__(16) char hb[2][4096];

    uint4 wfx[4][4], wfh[4][4];
    {
        const char* Wxg = (const char*)Wx;
        const char* Whg = (const char*)Wh;
#pragma unroll
        for (int G = 0; G < 4; ++G) {
            int row = G * 128 + myu;
#pragma unroll
            for (int kf = 0; kf < 4; ++kf) {
                int colb = (kf * 32 + (lane >> 4) * 8) * 2;
                wfx[G][kf] = *(const uint4*)(Wxg + (size_t)row * 256 + colb);
                wfh[G][kf] = *(const uint4*)(Whg + (size_t)row * 256 + colb);
            }
        }
    }
#pragma unroll
    for (int G = 0; G < 4; ++G)
#pragma unroll
        for (int kf = 0; kf < 4; ++kf) {
            asm volatile("" : "+v"(wfx[G][kf].x), "+v"(wfx[G][kf].y),
                              "+v"(wfx[G][kf].z), "+v"(wfx[G][kf].w));
            asm volatile("" : "+v"(wfh[G][kf].x), "+v"(wfh[G][kf].y),
                              "+v"(wfh[G][kf].z), "+v"(wfh[G][kf].w));
        }

    float bv[4];
#pragma unroll
    for (int G = 0; G < 4; ++G) bv[G] = bias[G * 128 + myu];

    float c[4] = {0.0f, 0.0f, 0.0f, 0.0f};

    ((unsigned int*)hb)[tid]       = 0u;
    ((unsigned int*)hb)[tid + 512] = 0u;
    __syncthreads();

    const char* xgb = (const char*)xb +
        ((size_t)(br0 + (lane & 15)) * 128 + (lane >> 4) * 8) * 2;
    const size_t XSTEP = (size_t)BB * 128 * 2;

    uint4 xafA[4], xafB[4];
#pragma unroll
    for (int kf = 0; kf < 4; ++kf) xafA[kf] = *(const uint4*)(xgb + kf * 64);
    float4v xacc[4];
#pragma unroll
    for (int G = 0; G < 4; ++G) {
        float4v t0 = {bv[G], bv[G], bv[G], bv[G]};
#pragma unroll
        for (int kf = 0; kf < 4; ++kf)
            t0 = __builtin_amdgcn_mfma_f32_16x16x32_bf16(
                __builtin_bit_cast(short8v, xafA[kf]),
                __builtin_bit_cast(short8v, wfx[G][kf]), t0, 0, 0, 0);
        xacc[G] = t0;
    }
#pragma unroll
    for (int kf = 0; kf < 4; ++kf) xafB[kf] = *(const uint4*)(xgb + XSTEP + kf * 64);

    int cur = 0;
    for (int t = 0; t < T_TOT; ++t) {
        short8v afh[4];
#pragma unroll
        for (int kf = 0; kf < 4; ++kf) {
            int row  = lane & 15;
            int byte = (row * 256 + kf * 64 + (lane >> 4) * 16) ^ ((row & 7) << 4);
            afh[kf] = *(const short8v*)(hb[cur] + byte);
        }
        float4v acc[4];
#pragma unroll
        for (int G = 0; G < 4; ++G) {
            float4v a = xacc[G];
#pragma unroll
            for (int kf = 0; kf < 4; ++kf)
                a = __builtin_amdgcn_mfma_f32_16x16x32_bf16(
                    afh[kf], __builtin_bit_cast(short8v, wfh[G][kf]), a, 0, 0, 0);
            acc[G] = a;
        }
#pragma unroll
        for (int kf = 0; kf < 4; ++kf) xafA[kf] = xafB[kf];
        if (t + 2 < T_TOT) {
            const char* xn = xgb + (size_t)(t + 2) * XSTEP;
#pragma unroll
            for (int kf = 0; kf < 4; ++kf) xafB[kf] = *(const uint4*)(xn + kf * 64);
        }
#pragma unroll
        for (int G = 0; G < 4; ++G) {
            float4v a = {bv[G], bv[G], bv[G], bv[G]};
#pragma unroll
            for (int kf = 0; kf < 4; ++kf)
                a = __builtin_amdgcn_mfma_f32_16x16x32_bf16(
                    __builtin_bit_cast(short8v, xafA[kf]),
                    __builtin_bit_cast(short8v, wfx[G][kf]), a, 0, 0, 0);
            xacc[G] = a;
        }
#pragma unroll
        for (int r = 0; r < 4; ++r) {
            float i_ = sigm(acc[0][r]);
            float f_ = sigm(acc[1][r]);
            float g_ = tanh_(acc[2][r]);
            float o_ = sigm(acc[3][r]);
            c[r] = fmaf(f_, c[r], i_ * g_);
            float h = o_ * tanh_(c[r]);
            unsigned short h16 = f2bf(h);
            int br   = (lane >> 4) * 4 + r;
            int byte = (br * 256 + myu * 2) ^ ((br & 7) << 4);
            *(unsigned short*)(hb[cur ^ 1] + byte) = h16;
            ((unsigned short*)hout)[((size_t)t * BB + br0 + br) * 128 + myu] = h16;
        }
        __syncthreads();
        cur ^= 1;
    }
}

// ---------------------------------------------------------------------------
// scan23_fused: 16 blocks x 320 thr (5 waves). Waves 0-3: layer 2. Wave 4:
// layer 3 (one step behind), including the h3*Whh3 recurrence term.
// ---------------------------------------------------------------------------
__global__ __launch_bounds__(320, 2) void scan23_fused(
    const __hip_bfloat16* __restrict__ h1b,  // [T, BB, 128]
    const __hip_bfloat16* __restrict__ Wx2,  // [256, 128] Wih2 bf16
    const __hip_bfloat16* __restrict__ Wh2,  // [256, 64]  Whh2 bf16
    const float* __restrict__ bias2,         // [256]
    const float* __restrict__ Wx3,           // [4, 64] f32 (raw input)
    const float* __restrict__ Wh3,           // [4, 1]  f32 (raw input)
    const float* __restrict__ bias3,         // [4]
    float* __restrict__ out)                 // [T, BB]
{
    const int tid  = threadIdx.x;
    const int lane = tid & 63;
    const int wid  = tid >> 6;     // 0..4
    const int br0  = blockIdx.x * 16;

    __shared__ __align__(16) char  h2b[2][2048];
    __shared__ __align__(16) float h2f[2][16][68];
    __shared__ float g3[64];

    if (wid < 4) {
        const int myu = wid * 16 + (lane & 15);

        uint4 wfx[4][4], wfh[4][2];
        {
            const char* Wxg = (const char*)Wx2;
            const char* Whg = (const char*)Wh2;
#pragma unroll
            for (int G = 0; G < 4; ++G) {
                int row = G * 64 + myu;
#pragma unroll
                for (int kf = 0; kf < 4; ++kf)
                    wfx[G][kf] = *(const uint4*)(Wxg + (size_t)row * 256 +
                                                 (kf * 32 + (lane >> 4) * 8) * 2);
#pragma unroll
                for (int kf = 0; kf < 2; ++kf)
                    wfh[G][kf] = *(const uint4*)(Whg + (size_t)row * 128 +
                                                 (kf * 32 + (lane >> 4) * 8) * 2);
            }
        }
#pragma unroll
        for (int G = 0; G < 4; ++G) {
#pragma unroll
            for (int kf = 0; kf < 4; ++kf)
                asm volatile("" : "+v"(wfx[G][kf].x), "+v"(wfx[G][kf].y),
                                  "+v"(wfx[G][kf].z), "+v"(wfx[G][kf].w));
#pragma unroll
            for (int kf = 0; kf < 2; ++kf)
                asm volatile("" : "+v"(wfh[G][kf].x), "+v"(wfh[G][kf].y),
                                  "+v"(wfh[G][kf].z), "+v"(wfh[G][kf].w));
        }

        float bv[4];
#pragma unroll
        for (int G = 0; G < 4; ++G) bv[G] = bias2[G * 64 + myu];

        float c[4] = {0.0f, 0.0f, 0.0f, 0.0f};

        ((unsigned int*)h2b)[tid]       = 0u;
        ((unsigned int*)h2b)[tid + 256] = 0u;
        {
            float* z = &h2f[0][0][0];
            for (int j = tid; j < 16 * 68; j += 256) z[j] = 0.0f;
        }

        const char* xgb = (const char*)h1b +
            ((size_t)(br0 + (lane & 15)) * 128 + (lane >> 4) * 8) * 2;
        const size_t XSTEP = (size_t)BB * 128 * 2;

        uint4 xafA[4], xafB[4];
#pragma unroll
        for (int kf = 0; kf < 4; ++kf) xafA[kf] = *(const uint4*)(xgb + kf * 64);
        float4v xacc[4];
#pragma unroll
        for (int G = 0; G < 4; ++G) {
            float4v t0 = {bv[G], bv[G], bv[G], bv[G]};
#pragma unroll
            for (int kf = 0; kf < 4; ++kf)
                t0 = __builtin_amdgcn_mfma_f32_16x16x32_bf16(
                    __builtin_bit_cast(short8v, xafA[kf]),
                    __builtin_bit_cast(short8v, wfx[G][kf]), t0, 0, 0, 0);
            xacc[G] = t0;
        }
#pragma unroll
        for (int kf = 0; kf < 4; ++kf) xafB[kf] = *(const uint4*)(xgb + XSTEP + kf * 64);

        __syncthreads();   // pre-loop barrier (matches wave4)

        for (int t = 0; t <= T_TOT; ++t) {
            if (t < T_TOT) {
                int cur = t & 1;
                short8v afh[2];
#pragma unroll
                for (int kf = 0; kf < 2; ++kf) {
                    int row  = lane & 15;
                    int byte = (row * 128 + kf * 64 + (lane >> 4) * 16) ^ ((row & 7) << 4);
                    afh[kf] = *(const short8v*)(h2b[cur] + byte);
                }
                float4v acc[4];
#pragma unroll
                for (int G = 0; G < 4; ++G) {
                    float4v a = xacc[G];
#pragma unroll
                    for (int kf = 0; kf < 2; ++kf)
                        a = __builtin_amdgcn_mfma_f32_16x16x32_bf16(
                            afh[kf], __builtin_bit_cast(short8v, wfh[G][kf]), a, 0, 0, 0);
                    acc[G] = a;
                }
#pragma unroll
                for (int kf = 0; kf < 4; ++kf) xafA[kf] = xafB[kf];
                if (t + 2 < T_TOT) {
                    const char* xn = xgb + (size_t)(t + 2) * XSTEP;
#pragma unroll
                    for (int kf = 0; kf < 4; ++kf) xafB[kf] = *(const uint4*)(xn + kf * 64);
                }
#pragma unroll
                for (int G = 0; G < 4; ++G) {
                    float4v a = {bv[G], bv[G], bv[G], bv[G]};
#pragma unroll
                    for (int kf = 0; kf < 4; ++kf)
                        a = __builtin_amdgcn_mfma_f32_16x16x32_bf16(
                            __builtin_bit_cast(short8v, xafA[kf]),
                            __builtin_bit_cast(short8v, wfx[G][kf]), a, 0, 0, 0);
                    xacc[G] = a;
                }
#pragma unroll
                for (int r = 0; r < 4; ++r) {
                    float i_ = sigm(acc[0][r]);
                    float f_ = sigm(acc[1][r]);
                    float g_ = tanh_(acc[2][r]);
                    float o_ = sigm(acc[3][r]);
                    c[r] = fmaf(f_, c[r], i_ * g_);
                    float h = o_ * tanh_(c[r]);
                    int br   = (lane >> 4) * 4 + r;
                    int byte = (br * 128 + myu * 2) ^ ((br & 7) << 4);
                    *(unsigned short*)(h2b[cur ^ 1] + byte) = f2bf(h);
                    h2f[cur ^ 1][br][myu] = h;
                }
            }
            __syncthreads();
        }
    } else {
        // ---- wave 4: layer 3 (H=1), one step behind ----
        const int row  = lane >> 2;     // 0..15
        const int gate = lane & 3;
        float4 w3[16];
        {
            const float4* w3p = (const float4*)(Wx3 + gate * 64);
#pragma unroll
            for (int j = 0; j < 16; ++j) w3[j] = w3p[j];
        }
        float bv3  = bias3[gate];
        float wh3  = Wh3[gate];          // Whh3[gate][0]
        float c3 = 0.0f, h3 = 0.0f;      // valid in lanes 0-15 (row state)

        __syncthreads();   // pre-loop barrier

        for (int t = 0; t <= T_TOT; ++t) {
            if (t >= 1) {
                const float* hrow = &h2f[t & 1][row][0];
                float a = bv3;
#pragma unroll
                for (int j = 0; j < 16; ++j) {
                    float4 hv = ((const float4*)hrow)[j];
                    float4 wv = w3[j];
                    a = fmaf(hv.x, wv.x, a);
                    a = fmaf(hv.y, wv.y, a);
                    a = fmaf(hv.z, wv.z, a);
                    a = fmaf(hv.w, wv.w, a);
                }
                g3[lane] = a;
                if (lane < 16) {
                    float4 gg = *(const float4*)(g3 + lane * 4);
                    // add h3*Whh3 recurrence term per gate
                    float gi = fmaf(h3, wh3, gg.x);          // wh3 differs per lane? no:
                    // lanes 0-15 each need all 4 whh3 values; load from LDS-free path:
                    float w0 = Wh3[0], w1 = Wh3[1], w2 = Wh3[2], w3s = Wh3[3];
                    gi       = fmaf(h3, w0, gg.x);
                    float gf = fmaf(h3, w1, gg.y);
                    float gg_ = fmaf(h3, w2, gg.z);
                    float go = fmaf(h3, w3s, gg.w);
                    float i_ = sigm(gi);
                    float f_ = sigm(gf);
                    float g_ = tanh_(gg_);
                    float o_ = sigm(go);
                    c3 = fmaf(f_, c3, i_ * g_);
                    h3 = o_ * tanh_(c3);
                    out[(size_t)(t - 1) * BB + br0 + lane] = h3;
                }
            }
            __syncthreads();
        }
    }
}

// ---------------------------------------------------------------------------
extern "C" void kernel_launch(void* const* d_in, const int* in_sizes, int n_in,
                              void* d_out, int out_size, void* d_ws, size_t ws_size,
                              hipStream_t stream) {
    const float* x    = (const float*)d_in[0];
    const float* Wih1 = (const float*)d_in[1];
    const float* Whh1 = (const float*)d_in[2];
    const float* bih1 = (const float*)d_in[3];
    const float* bhh1 = (const float*)d_in[4];
    const float* Wih2 = (const float*)d_in[5];
    const float* Whh2 = (const float*)d_in[6];
    const float* bih2 = (const float*)d_in[7];
    const float* bhh2 = (const float*)d_in[8];
    const float* Wih3 = (const float*)d_in[9];
    const float* Whh3 = (const float*)d_in[10];
    const float* bih3 = (const float*)d_in[11];
    const float* bhh3 = (const float*)d_in[12];
    float* out = (float*)d_out;

    char* ws = (char*)d_ws;
    __hip_bfloat16* xb    = (__hip_bfloat16*)(ws + 0);          // 33,554,432
    __hip_bfloat16* h1b   = (__hip_bfloat16*)(ws + 33554432);   // 33,554,432
    __hip_bfloat16* wb1   = (__hip_bfloat16*)(ws + 67108864);   //    131,072
    __hip_bfloat16* whb1  = (__hip_bfloat16*)(ws + 67239936);   //    131,072
    __hip_bfloat16* wb2   = (__hip_bfloat16*)(ws + 67371008);   //     65,536
    __hip_bfloat16* whb2  = (__hip_bfloat16*)(ws + 67436544);   //     32,768
    float*          bias1 = (float*)(ws + 67469312);            //      2,048
    float*          bias2 = (float*)(ws + 67471360);            //      1,024
    float*          bias3 = (float*)(ws + 67472384);            //         16

    cvt_pad<<<4096, 256, 0, stream>>>(x, xb, T_TOT * BB, 97);
    cvt_pad<<<256, 256, 0, stream>>>(Wih1, wb1, 512, 97);
    cvt_plain<<<256, 256, 0, stream>>>(Whh1, whb1, 512 * 128);
    cvt_plain<<<128, 256, 0, stream>>>(Wih2, wb2, 256 * 128);
    cvt_plain<<<64, 256, 0, stream>>>(Whh2, whb2, 256 * 64);
    addvec<<<2, 256, 0, stream>>>(bih1, bhh1, bias1, 512);
    addvec<<<1, 256, 0, stream>>>(bih2, bhh2, bias2, 256);
    addvec<<<1, 256, 0, stream>>>(bih3, bhh3, bias3, 4);

    scan1_fused<<<16, 512, 0, stream>>>(xb, wb1, whb1, bias1, h1b);
    scan23_fused<<<16, 320, 0, stream>>>(h1b, wb2, whb2, bias2, Wih3, Whh3, bias3, out);
}